// Round 10
// baseline (378.583 us; speedup 1.0000x reference)
//
#include <hip/hip_runtime.h>

#define N_NODES 50000
#define N_EDGES 800000
#define EA (N_EDGES + N_NODES)   // 850000 edges incl. self-loops
#define IN_CH 512
#define D1 256
#define HID 32
#define HEADS 8
#define NCLS 40
#define NCLS_P 48                // padded to 3 x 16 col-tiles
#define CAP 64                   // bucket capacity (max degree ~36)
#define NEG 0.2f

typedef unsigned short u16;
typedef unsigned int u32;
typedef __attribute__((ext_vector_type(8))) short bf16x8;
typedef __attribute__((ext_vector_type(4))) float f32x4;

__device__ inline u16 f2bf(float f) {           // round-to-nearest-even fp32->bf16
  u32 u = __float_as_uint(f);
  u += 0x7FFFu + ((u >> 16) & 1u);
  return (u16)(u >> 16);
}
__device__ inline u32 pack2(float a, float b) {
  return (u32)f2bf(a) | ((u32)f2bf(b) << 16);
}
__device__ inline float bflo(u32 v) { return __uint_as_float(v << 16); }
__device__ inline float bfhi(u32 v) { return __uint_as_float(v & 0xffff0000u); }

// ---------------- merged prep: bucket build + weight casts (one launch) ----------------
#define NB_BUCKET ((EA + 255) / 256)
__global__ __launch_bounds__(256) void k_prep(const int* __restrict__ ei,
                                              int* __restrict__ cnt,
                                              u32* __restrict__ buck,
                                              const float* __restrict__ W1,
                                              const float* __restrict__ W2,
                                              u16* __restrict__ w1t,
                                              u16* __restrict__ w2t) {
  int bid = blockIdx.x;
  if (bid < NB_BUCKET) {
    int e = bid * 256 + threadIdx.x;
    if (e >= EA) return;
    int src, dst;
    if (e < N_EDGES) { src = ei[e]; dst = ei[N_EDGES + e]; }
    else             { src = e - N_EDGES; dst = src; }
    int pos = atomicAdd(&cnt[dst], 1);
    if (pos < CAP) buck[dst * CAP + pos] = (u32)src;
  } else {
    int id = (bid - NB_BUCKET) * 256 + threadIdx.x;
    if (id < D1 * IN_CH) {
      int n = id >> 9, k = id & 511;
      w1t[id] = f2bf(W1[(size_t)k * D1 + n]);
    } else {
      int id2 = id - D1 * IN_CH;
      if (id2 < NCLS_P * D1) {
        int n = id2 >> 8, k = id2 & 255;
        w2t[id2] = (n < NCLS) ? f2bf(W2[(size_t)k * NCLS + n]) : (u16)0;
      }
    }
  }
}

// ---------------- GEMM1 (bf16 MFMA, 2-deep X prefetch + counted vmcnt + FUSED al1) ----------------
// X(k+2) issued at step k and left IN FLIGHT across the barrier (vmcnt(2) waits only the
// B stage). X HBM latency (~900cy) now has a full step+compute to land, vs <300cy before.
__global__ __launch_bounds__(256) void k_gemm1_fused(const float* __restrict__ X,   // [M,512] fp32
                                                     const u16* __restrict__ BT,    // [256,512] bf16
                                                     const float* __restrict__ AS,  // att_src1 [256]
                                                     const float* __restrict__ AD,  // att_dst1 [256]
                                                     u16* __restrict__ Cb,          // [M,256] bf16
                                                     float* __restrict__ al_s,      // [M*8]
                                                     float* __restrict__ al_d) {    // [M*8]
  __shared__ u16 As[2][64 * 32];    // 8 KB
  __shared__ u16 Bs[2][256 * 32];   // 32 KB
  const int M = N_NODES;
  int bm = blockIdx.x * 64;
  int t = threadIdx.x;
  int lane = t & 63, wave = t >> 6;
  int wm = (wave & 1) * 32, wn = (wave >> 1) * 128;
  int lr = lane & 15;

  int arow = t >> 2;
  int akofs = (t & 3) * 8;
  int garow = bm + arow; if (garow >= M) garow = M - 1;
  const float* xrow = &X[(size_t)garow * IN_CH + akofs];

  int brow_base = wave * 64;
  int blrow = lane >> 2;
  int bkofs = (lane & 3) * 8;

  int kq = (lane >> 4) * 8;

  f32x4 acc[2][8] = {};

  // ---- prologue: B(0) staged, X(0) packed, X(32) issued (stays in flight)
  #pragma unroll
  for (int q = 0; q < 4; ++q) {
    int r0 = brow_base + q * 16;
    __builtin_amdgcn_global_load_lds(
        (const __attribute__((address_space(1))) void*)&BT[(size_t)(r0 + blrow) * IN_CH + bkofs],
        (__attribute__((address_space(3))) void*)&Bs[0][r0 * 32], 16, 0, 0);
  }
  {
    float4 v0 = *(const float4*)xrow;
    float4 v1 = *(const float4*)(xrow + 4);
    uint4 o;
    o.x = pack2(v0.x, v0.y); o.y = pack2(v0.z, v0.w);
    o.z = pack2(v1.x, v1.y); o.w = pack2(v1.z, v1.w);
    *(uint4*)&As[0][arow * 32 + akofs] = o;
  }
  float4 xn1a = *(const float4*)(xrow + 32);
  float4 xn1b = *(const float4*)(xrow + 36);
  asm volatile("s_waitcnt lgkmcnt(0)" ::: "memory");
  __builtin_amdgcn_s_barrier();
  __builtin_amdgcn_sched_barrier(0);

  int cur = 0;
  // full iterations: stage B(k0), issue X(k0+32), compute k0-32
  for (int k0 = 32; k0 <= IN_CH - 64; k0 += 32) {
    int nxt = cur ^ 1;
    #pragma unroll
    for (int q = 0; q < 4; ++q) {
      int r0 = brow_base + q * 16;
      __builtin_amdgcn_global_load_lds(
          (const __attribute__((address_space(1))) void*)&BT[(size_t)(r0 + blrow) * IN_CH + k0 + bkofs],
          (__attribute__((address_space(3))) void*)&Bs[nxt][r0 * 32], 16, 0, 0);
    }
    float4 xn2a = *(const float4*)(xrow + k0 + 32);
    float4 xn2b = *(const float4*)(xrow + k0 + 36);

    bf16x8 af[2], bfr[8];
    #pragma unroll
    for (int i = 0; i < 2; ++i)
      af[i] = *(const bf16x8*)&As[cur][(wm + i * 16 + lr) * 32 + kq];
    #pragma unroll
    for (int j = 0; j < 8; ++j)
      bfr[j] = *(const bf16x8*)&Bs[cur][(wn + j * 16 + lr) * 32 + kq];
    #pragma unroll
    for (int i = 0; i < 2; ++i)
      #pragma unroll
      for (int j = 0; j < 8; ++j)
        acc[i][j] = __builtin_amdgcn_mfma_f32_16x16x32_bf16(af[i], bfr[j], acc[i][j], 0, 0, 0);

    // pack X(k0) (issued last step; compiler inserts the counted wait for these regs)
    uint4 o;
    o.x = pack2(xn1a.x, xn1a.y); o.y = pack2(xn1a.z, xn1a.w);
    o.z = pack2(xn1b.x, xn1b.y); o.w = pack2(xn1b.z, xn1b.w);
    *(uint4*)&As[nxt][arow * 32 + akofs] = o;
    xn1a = xn2a; xn1b = xn2b;
    // wait B(k0) (4 loads) + ds_write; X(k0+32)'s 2 loads stay in flight across barrier
    asm volatile("s_waitcnt vmcnt(2) lgkmcnt(0)" ::: "memory");
    __builtin_amdgcn_s_barrier();
    __builtin_amdgcn_sched_barrier(0);
    cur = nxt;
  }

  // k0 = 480: stage last B tile, compute tile 448, pack X(480); full drain
  {
    const int k0 = IN_CH - 32;
    int nxt = cur ^ 1;
    #pragma unroll
    for (int q = 0; q < 4; ++q) {
      int r0 = brow_base + q * 16;
      __builtin_amdgcn_global_load_lds(
          (const __attribute__((address_space(1))) void*)&BT[(size_t)(r0 + blrow) * IN_CH + k0 + bkofs],
          (__attribute__((address_space(3))) void*)&Bs[nxt][r0 * 32], 16, 0, 0);
    }
    bf16x8 af[2], bfr[8];
    #pragma unroll
    for (int i = 0; i < 2; ++i)
      af[i] = *(const bf16x8*)&As[cur][(wm + i * 16 + lr) * 32 + kq];
    #pragma unroll
    for (int j = 0; j < 8; ++j)
      bfr[j] = *(const bf16x8*)&Bs[cur][(wn + j * 16 + lr) * 32 + kq];
    #pragma unroll
    for (int i = 0; i < 2; ++i)
      #pragma unroll
      for (int j = 0; j < 8; ++j)
        acc[i][j] = __builtin_amdgcn_mfma_f32_16x16x32_bf16(af[i], bfr[j], acc[i][j], 0, 0, 0);
    uint4 o;
    o.x = pack2(xn1a.x, xn1a.y); o.y = pack2(xn1a.z, xn1a.w);
    o.z = pack2(xn1b.x, xn1b.y); o.w = pack2(xn1b.z, xn1b.w);
    *(uint4*)&As[nxt][arow * 32 + akofs] = o;
    asm volatile("s_waitcnt vmcnt(0) lgkmcnt(0)" ::: "memory");
    __builtin_amdgcn_s_barrier();
    __builtin_amdgcn_sched_barrier(0);
    cur = nxt;
  }

  // final tile (cols 480..511): compute only
  {
    bf16x8 af[2], bfr[8];
    #pragma unroll
    for (int i = 0; i < 2; ++i)
      af[i] = *(const bf16x8*)&As[cur][(wm + i * 16 + lr) * 32 + kq];
    #pragma unroll
    for (int j = 0; j < 8; ++j)
      bfr[j] = *(const bf16x8*)&Bs[cur][(wn + j * 16 + lr) * 32 + kq];
    #pragma unroll
    for (int i = 0; i < 2; ++i)
      #pragma unroll
      for (int j = 0; j < 8; ++j)
        acc[i][j] = __builtin_amdgcn_mfma_f32_16x16x32_bf16(af[i], bfr[j], acc[i][j], 0, 0, 0);
  }

  // C-write
  #pragma unroll
  for (int i = 0; i < 2; ++i) {
    #pragma unroll
    for (int j = 0; j < 8; ++j) {
      int col = wn + j * 16 + lr;
      int rowb = bm + wm + i * 16 + (lane >> 4) * 4;
      #pragma unroll
      for (int r = 0; r < 4; ++r) {
        int row = rowb + r;
        if (row < M) Cb[(size_t)row * D1 + col] = f2bf(acc[i][j][r]);
      }
    }
  }

  // fused al1
  float as_r[8], ad_r[8];
  #pragma unroll
  for (int j = 0; j < 8; ++j) {
    as_r[j] = AS[wn + j * 16 + lr];
    ad_r[j] = AD[wn + j * 16 + lr];
  }
  int hbase = wn >> 5;   // 0 or 4
  int c = lr;
  #pragma unroll
  for (int i = 0; i < 2; ++i) {
    #pragma unroll
    for (int r = 0; r < 4; ++r) {
      float ps0 = acc[i][0][r] * as_r[0] + acc[i][1][r] * as_r[1];
      float ps1 = acc[i][2][r] * as_r[2] + acc[i][3][r] * as_r[3];
      float ps2 = acc[i][4][r] * as_r[4] + acc[i][5][r] * as_r[5];
      float ps3 = acc[i][6][r] * as_r[6] + acc[i][7][r] * as_r[7];
      float pd0 = acc[i][0][r] * ad_r[0] + acc[i][1][r] * ad_r[1];
      float pd1 = acc[i][2][r] * ad_r[2] + acc[i][3][r] * ad_r[3];
      float pd2 = acc[i][4][r] * ad_r[4] + acc[i][5][r] * ad_r[5];
      float pd3 = acc[i][6][r] * ad_r[6] + acc[i][7][r] * ad_r[7];
      #pragma unroll
      for (int s = 1; s < 16; s <<= 1) {
        ps0 += __shfl_xor(ps0, s, 64); ps1 += __shfl_xor(ps1, s, 64);
        ps2 += __shfl_xor(ps2, s, 64); ps3 += __shfl_xor(ps3, s, 64);
        pd0 += __shfl_xor(pd0, s, 64); pd1 += __shfl_xor(pd1, s, 64);
        pd2 += __shfl_xor(pd2, s, 64); pd3 += __shfl_xor(pd3, s, 64);
      }
      int row = bm + wm + i * 16 + (lane >> 4) * 4 + r;
      if (c < 4 && row < M) {
        float ps = (c == 0) ? ps0 : (c == 1) ? ps1 : (c == 2) ? ps2 : ps3;
        float pd = (c == 0) ? pd0 : (c == 1) ? pd1 : (c == 2) ? pd2 : pd3;
        al_s[(size_t)row * 8 + hbase + c] = ps;
        al_d[(size_t)row * 8 + hbase + c] = pd;
      }
    }
  }
}

// ---------------- layer-1 aggregate + bias + ELU (round-1 best form) ----------------
__global__ __launch_bounds__(256) void k_agg1(const int* __restrict__ cnt,
                                              const u32* __restrict__ buck,
                                              const float* __restrict__ al_s,
                                              const float* __restrict__ al_d,
                                              const u16* __restrict__ h1b,
                                              const float* __restrict__ b1,
                                              u32* __restrict__ x2b) {
  int node = (blockIdx.x * 256 + threadIdx.x) >> 6;
  int lane = threadIdx.x & 63;
  if (node >= N_NODES) return;
  int cn = cnt[node]; if (cn > CAP) cn = CAP;
  const u32* br = &buck[(size_t)node * CAP];
  int h3 = lane >> 3;
  float ad = al_d[node * 8 + h3];
  size_t choff = (size_t)lane * 4;
  float dsum = 0.f;
  float4 acc = make_float4(0.f, 0.f, 0.f, 0.f);
  int j = 0;
  for (; j + 8 <= cn; j += 8) {
    int s0 = br[j + 0], s1 = br[j + 1], s2 = br[j + 2], s3 = br[j + 3];
    int s4 = br[j + 4], s5 = br[j + 5], s6 = br[j + 6], s7 = br[j + 7];
    float e0 = al_s[s0 * 8 + h3] + ad, e1 = al_s[s1 * 8 + h3] + ad;
    float e2 = al_s[s2 * 8 + h3] + ad, e3 = al_s[s3 * 8 + h3] + ad;
    float e4 = al_s[s4 * 8 + h3] + ad, e5 = al_s[s5 * 8 + h3] + ad;
    float e6 = al_s[s6 * 8 + h3] + ad, e7 = al_s[s7 * 8 + h3] + ad;
    uint2 hv0 = *(const uint2*)&h1b[(size_t)s0 * D1 + choff];
    uint2 hv1 = *(const uint2*)&h1b[(size_t)s1 * D1 + choff];
    uint2 hv2 = *(const uint2*)&h1b[(size_t)s2 * D1 + choff];
    uint2 hv3 = *(const uint2*)&h1b[(size_t)s3 * D1 + choff];
    uint2 hv4 = *(const uint2*)&h1b[(size_t)s4 * D1 + choff];
    uint2 hv5 = *(const uint2*)&h1b[(size_t)s5 * D1 + choff];
    uint2 hv6 = *(const uint2*)&h1b[(size_t)s6 * D1 + choff];
    uint2 hv7 = *(const uint2*)&h1b[(size_t)s7 * D1 + choff];
    e0 = (e0 > 0.f) ? e0 : NEG * e0;  e1 = (e1 > 0.f) ? e1 : NEG * e1;
    e2 = (e2 > 0.f) ? e2 : NEG * e2;  e3 = (e3 > 0.f) ? e3 : NEG * e3;
    e4 = (e4 > 0.f) ? e4 : NEG * e4;  e5 = (e5 > 0.f) ? e5 : NEG * e5;
    e6 = (e6 > 0.f) ? e6 : NEG * e6;  e7 = (e7 > 0.f) ? e7 : NEG * e7;
    float pp0 = __expf(e0), pp1 = __expf(e1), pp2 = __expf(e2), pp3 = __expf(e3);
    float pp4 = __expf(e4), pp5 = __expf(e5), pp6 = __expf(e6), pp7 = __expf(e7);
    dsum += ((pp0 + pp1) + (pp2 + pp3)) + ((pp4 + pp5) + (pp6 + pp7));
    acc.x += pp0 * bflo(hv0.x) + pp1 * bflo(hv1.x) + pp2 * bflo(hv2.x) + pp3 * bflo(hv3.x)
           + pp4 * bflo(hv4.x) + pp5 * bflo(hv5.x) + pp6 * bflo(hv6.x) + pp7 * bflo(hv7.x);
    acc.y += pp0 * bfhi(hv0.x) + pp1 * bfhi(hv1.x) + pp2 * bfhi(hv2.x) + pp3 * bfhi(hv3.x)
           + pp4 * bfhi(hv4.x) + pp5 * bfhi(hv5.x) + pp6 * bfhi(hv6.x) + pp7 * bfhi(hv7.x);
    acc.z += pp0 * bflo(hv0.y) + pp1 * bflo(hv1.y) + pp2 * bflo(hv2.y) + pp3 * bflo(hv3.y)
           + pp4 * bflo(hv4.y) + pp5 * bflo(hv5.y) + pp6 * bflo(hv6.y) + pp7 * bflo(hv7.y);
    acc.w += pp0 * bfhi(hv0.y) + pp1 * bfhi(hv1.y) + pp2 * bfhi(hv2.y) + pp3 * bfhi(hv3.y)
           + pp4 * bfhi(hv4.y) + pp5 * bfhi(hv5.y) + pp6 * bfhi(hv6.y) + pp7 * bfhi(hv7.y);
  }
  for (; j < cn; ++j) {
    int s0 = br[j];
    float e0 = al_s[s0 * 8 + h3] + ad;
    e0 = (e0 > 0.f) ? e0 : NEG * e0;
    float pp0 = __expf(e0);
    uint2 hv0 = *(const uint2*)&h1b[(size_t)s0 * D1 + choff];
    dsum += pp0;
    acc.x += pp0 * bflo(hv0.x);
    acc.y += pp0 * bfhi(hv0.x);
    acc.z += pp0 * bflo(hv0.y);
    acc.w += pp0 * bfhi(hv0.y);
  }
  float inv = 1.f / (dsum + 1e-16f);
  float4 bb = *(const float4*)&b1[lane * 4];
  float vx = acc.x * inv + bb.x; vx = vx > 0.f ? vx : __expf(vx) - 1.f;
  float vy = acc.y * inv + bb.y; vy = vy > 0.f ? vy : __expf(vy) - 1.f;
  float vz = acc.z * inv + bb.z; vz = vz > 0.f ? vz : __expf(vz) - 1.f;
  float vw = acc.w * inv + bb.w; vw = vw > 0.f ? vw : __expf(vw) - 1.f;
  ((uint2*)x2b)[(size_t)node * 64 + lane] = make_uint2(pack2(vx, vy), pack2(vz, vw));
}

// ---------------- GEMM2 (bf16 MFMA, ONE-SHOT panel stage, 1 barrier + FUSED al2) ----------------
// BM=64: whole 64x256 A-panel (32 KB) staged with 8 global_load_lds per thread, ONE
// vmcnt(0)+barrier, then all 8 K-steps barrier-free (B from L1-resident 24 KB w2t).
__global__ __launch_bounds__(256) void k_gemm2_mfma(const u16* __restrict__ A,     // [M,256] bf16
                                                    const u16* __restrict__ W2T,   // [48][256] bf16
                                                    const float* __restrict__ AS2, // att_src2 [40]
                                                    const float* __restrict__ AD2, // att_dst2 [40]
                                                    u16* __restrict__ h2b,         // [M,40] bf16
                                                    float* __restrict__ al_s2,     // [M]
                                                    float* __restrict__ al_d2) {   // [M]
  __shared__ u16 As[8][64 * 32];        // 32 KB: 8 K-tiles of [64 rows][32 cols]
  const int M = N_NODES;
  int bm = blockIdx.x * 64;
  int t = threadIdx.x;
  int lane = t & 63, wave = t >> 6;
  int wm = wave * 16;
  int lr = lane & 15;
  int kq = (lane >> 4) * 8;

  // one-shot stage: per tile, wave w covers rows wm..wm+15 (lane>>2), cols (lane&3)*8
  {
    int srow = bm + wm + (lane >> 2); if (srow >= M) srow = M - 1;
    int skof = (lane & 3) * 8;
    const u16* ap = &A[(size_t)srow * D1 + skof];
    #pragma unroll
    for (int tt = 0; tt < 8; ++tt) {
      __builtin_amdgcn_global_load_lds(
          (const __attribute__((address_space(1))) void*)(ap + tt * 32),
          (__attribute__((address_space(3))) void*)&As[tt][wm * 32], 16, 0, 0);
    }
  }
  asm volatile("s_waitcnt vmcnt(0) lgkmcnt(0)" ::: "memory");
  __builtin_amdgcn_s_barrier();
  __builtin_amdgcn_sched_barrier(0);

  const u16* wp = &W2T[(size_t)lr * D1 + kq];   // + j*16*D1 per frag, + tt*32 per step
  f32x4 acc[3] = {};
  #pragma unroll
  for (int tt = 0; tt < 8; ++tt) {
    bf16x8 af = *(const bf16x8*)&As[tt][(wm + lr) * 32 + kq];
    bf16x8 bfr[3];
    #pragma unroll
    for (int j = 0; j < 3; ++j)
      bfr[j] = *(const bf16x8*)(wp + (size_t)j * 16 * D1 + tt * 32);
    #pragma unroll
    for (int j = 0; j < 3; ++j)
      acc[j] = __builtin_amdgcn_mfma_f32_16x16x32_bf16(af, bfr[j], acc[j], 0, 0, 0);
  }

  // C-write
  #pragma unroll
  for (int j = 0; j < 3; ++j) {
    int col = j * 16 + lr;
    if (col >= NCLS) continue;
    int rowb = bm + wm + (lane >> 4) * 4;
    #pragma unroll
    for (int r = 0; r < 4; ++r) {
      int row = rowb + r;
      if (row < M) h2b[(size_t)row * NCLS + col] = f2bf(acc[j][r]);
    }
  }

  // fused al2
  float as2_r[3], ad2_r[3];
  #pragma unroll
  for (int j = 0; j < 3; ++j) {
    int col = j * 16 + lr;
    as2_r[j] = (col < NCLS) ? AS2[col] : 0.f;
    ad2_r[j] = (col < NCLS) ? AD2[col] : 0.f;
  }
  #pragma unroll
  for (int r = 0; r < 4; ++r) {
    float ps = acc[0][r] * as2_r[0] + acc[1][r] * as2_r[1] + acc[2][r] * as2_r[2];
    float pd = acc[0][r] * ad2_r[0] + acc[1][r] * ad2_r[1] + acc[2][r] * ad2_r[2];
    #pragma unroll
    for (int s = 1; s < 16; s <<= 1) {
      ps += __shfl_xor(ps, s, 64);
      pd += __shfl_xor(pd, s, 64);
    }
    int row = bm + wm + (lane >> 4) * 4 + r;
    if (row < M) {
      if (lr == 0) al_s2[row] = ps;
      else if (lr == 1) al_d2[row] = pd;
    }
  }
}

// ---------------- layer-2 aggregate + bias: buckets, inline p, 4x unroll (round-1 best form) ----------------
__global__ __launch_bounds__(256) void k_agg2(const int* __restrict__ cnt,
                                              const u32* __restrict__ buck,
                                              const float* __restrict__ al_s,
                                              const float* __restrict__ al_d,
                                              const u32* __restrict__ h2p,
                                              const float* __restrict__ b2,
                                              float* __restrict__ out) {
  int node = (blockIdx.x * 256 + threadIdx.x) >> 6;
  int lane = threadIdx.x & 63;
  if (node >= N_NODES) return;
  int cn = cnt[node]; if (cn > CAP) cn = CAP;
  const u32* br = &buck[(size_t)node * CAP];
  float ad = al_d[node];
  int cl = (lane < NCLS / 2) ? lane : 0;
  float dsum = 0.f, accl = 0.f, acch = 0.f;
  int j = 0;
  for (; j + 4 <= cn; j += 4) {
    int s0 = br[j + 0], s1 = br[j + 1], s2 = br[j + 2], s3 = br[j + 3];
    float e0 = al_s[s0] + ad, e1 = al_s[s1] + ad;
    float e2 = al_s[s2] + ad, e3 = al_s[s3] + ad;
    u32 g0 = h2p[(size_t)s0 * (NCLS / 2) + cl];
    u32 g1 = h2p[(size_t)s1 * (NCLS / 2) + cl];
    u32 g2 = h2p[(size_t)s2 * (NCLS / 2) + cl];
    u32 g3 = h2p[(size_t)s3 * (NCLS / 2) + cl];
    e0 = (e0 > 0.f) ? e0 : NEG * e0;
    e1 = (e1 > 0.f) ? e1 : NEG * e1;
    e2 = (e2 > 0.f) ? e2 : NEG * e2;
    e3 = (e3 > 0.f) ? e3 : NEG * e3;
    float p0 = __expf(e0), p1 = __expf(e1), p2 = __expf(e2), p3 = __expf(e3);
    dsum += (p0 + p1) + (p2 + p3);
    accl += p0 * bflo(g0) + p1 * bflo(g1) + p2 * bflo(g2) + p3 * bflo(g3);
    acch += p0 * bfhi(g0) + p1 * bfhi(g1) + p2 * bfhi(g2) + p3 * bfhi(g3);
  }
  for (; j < cn; ++j) {
    int s0 = br[j];
    float e0 = al_s[s0] + ad;
    e0 = (e0 > 0.f) ? e0 : NEG * e0;
    float p0 = __expf(e0);
    u32 g0 = h2p[(size_t)s0 * (NCLS / 2) + cl];
    dsum += p0;
    accl += p0 * bflo(g0);
    acch += p0 * bfhi(g0);
  }
  float inv = 1.f / (dsum + 1e-16f);
  if (lane < NCLS / 2) {
    out[(size_t)node * NCLS + 2 * lane]     = accl * inv + b2[2 * lane];
    out[(size_t)node * NCLS + 2 * lane + 1] = acch * inv + b2[2 * lane + 1];
  }
}

extern "C" void kernel_launch(void* const* d_in, const int* in_sizes, int n_in,
                              void* d_out, int out_size, void* d_ws, size_t ws_size,
                              hipStream_t stream) {
  const float* x   = (const float*)d_in[0];
  const int*   ei  = (const int*)d_in[1];
  const float* W1  = (const float*)d_in[2];
  const float* as1 = (const float*)d_in[3];
  const float* ad1 = (const float*)d_in[4];
  const float* b1  = (const float*)d_in[5];
  const float* W2  = (const float*)d_in[6];
  const float* as2 = (const float*)d_in[7];
  const float* ad2 = (const float*)d_in[8];
  const float* b2  = (const float*)d_in[9];
  float* out = (float*)d_out;

  // workspace carve-up (~75 MB of the 400 MB ws)
  char* p = (char*)d_ws;
  auto alloc = [&](size_t bytes) { char* r = p; p += (bytes + 15) & ~size_t(15); return r; };
  u16*  h1b    = (u16*)alloc((size_t)N_NODES * D1 * 2);      // 25.6 MB bf16
  u32*  x2b    = (u32*)alloc((size_t)N_NODES * D1 * 2);      // 25.6 MB bf16 pairs
  u16*  h2b    = (u16*)alloc((size_t)N_NODES * NCLS * 2);    // 4 MB bf16
  float* al_s1 = (float*)alloc((size_t)N_NODES * 8 * 4);
  float* al_d1 = (float*)alloc((size_t)N_NODES * 8 * 4);
  float* al_s2 = (float*)alloc((size_t)N_NODES * 4);
  float* al_d2 = (float*)alloc((size_t)N_NODES * 4);
  int*   cnt   = (int*)alloc((size_t)N_NODES * 4);
  u32*   buck  = (u32*)alloc((size_t)N_NODES * CAP * 4);     // 12.8 MB
  u16*   w1t   = (u16*)alloc((size_t)D1 * IN_CH * 2);
  u16*   w2t   = (u16*)alloc((size_t)NCLS_P * D1 * 2);

  hipMemsetAsync(cnt, 0, (size_t)N_NODES * 4, stream);

  const int WTOT = D1 * IN_CH + NCLS_P * D1;
  const int NB_CAST = (WTOT + 255) / 256;
  k_prep<<<NB_BUCKET + NB_CAST, 256, 0, stream>>>(ei, cnt, buck, W1, W2, w1t, w2t);

  k_gemm1_fused<<<(N_NODES + 63) / 64, 256, 0, stream>>>(x, w1t, as1, ad1, h1b, al_s1, al_d1);
  k_agg1<<<(N_NODES + 3) / 4, 256, 0, stream>>>(cnt, buck, al_s1, al_d1, h1b, b1, x2b);

  k_gemm2_mfma<<<(N_NODES + 63) / 64, 256, 0, stream>>>((const u16*)x2b, w2t, as2, ad2, h2b, al_s2, al_d2);
  k_agg2<<<(N_NODES + 3) / 4, 256, 0, stream>>>(cnt, buck, al_s2, al_d2, (const u32*)h2b, b2, out);
}

// Round 12
// 366.472 us; speedup vs baseline: 1.0330x; 1.0330x over previous
//
#include <hip/hip_runtime.h>

#define N_NODES 50000
#define N_EDGES 800000
#define EA (N_EDGES + N_NODES)   // 850000 edges incl. self-loops
#define IN_CH 512
#define D1 256
#define HID 32
#define HEADS 8
#define NCLS 40
#define NCLS_P 48                // padded to 3 x 16 col-tiles
#define CAP 64                   // bucket capacity (max degree ~36)
#define NEG 0.2f

typedef unsigned short u16;
typedef unsigned int u32;
typedef __attribute__((ext_vector_type(8))) short bf16x8;
typedef __attribute__((ext_vector_type(4))) float f32x4;

__device__ inline u16 f2bf(float f) {           // round-to-nearest-even fp32->bf16
  u32 u = __float_as_uint(f);
  u += 0x7FFFu + ((u >> 16) & 1u);
  return (u16)(u >> 16);
}
__device__ inline u32 pack2(float a, float b) {
  return (u32)f2bf(a) | ((u32)f2bf(b) << 16);
}
__device__ inline float bflo(u32 v) { return __uint_as_float(v << 16); }
__device__ inline float bfhi(u32 v) { return __uint_as_float(v & 0xffff0000u); }

// ---------------- merged prep: bucket build + weight casts (one launch) ----------------
#define NB_BUCKET ((EA + 255) / 256)
__global__ __launch_bounds__(256) void k_prep(const int* __restrict__ ei,
                                              int* __restrict__ cnt,
                                              u32* __restrict__ buck,
                                              const float* __restrict__ W1,
                                              const float* __restrict__ W2,
                                              u16* __restrict__ w1t,
                                              u16* __restrict__ w2t) {
  int bid = blockIdx.x;
  if (bid < NB_BUCKET) {
    int e = bid * 256 + threadIdx.x;
    if (e >= EA) return;
    int src, dst;
    if (e < N_EDGES) { src = ei[e]; dst = ei[N_EDGES + e]; }
    else             { src = e - N_EDGES; dst = src; }
    int pos = atomicAdd(&cnt[dst], 1);
    if (pos < CAP) buck[dst * CAP + pos] = (u32)src;
  } else {
    int id = (bid - NB_BUCKET) * 256 + threadIdx.x;
    if (id < D1 * IN_CH) {
      int n = id >> 9, k = id & 511;
      w1t[id] = f2bf(W1[(size_t)k * D1 + n]);
    } else {
      int id2 = id - D1 * IN_CH;
      if (id2 < NCLS_P * D1) {
        int n = id2 >> 8, k = id2 & 255;
        w2t[id2] = (n < NCLS) ? f2bf(W2[(size_t)k * NCLS + n]) : (u16)0;
      }
    }
  }
}

// ---------------- GEMM1 (bf16 MFMA, LDS 2-phase dbuf, BN=256 + FUSED al1) — round-6 best ----------------
// Measured floor 76 us across 5 structures; vmcnt(0) drain per step is the best form.
__global__ __launch_bounds__(256) void k_gemm1_fused(const float* __restrict__ X,   // [M,512] fp32
                                                     const u16* __restrict__ BT,    // [256,512] bf16
                                                     const float* __restrict__ AS,  // att_src1 [256]
                                                     const float* __restrict__ AD,  // att_dst1 [256]
                                                     u16* __restrict__ Cb,          // [M,256] bf16
                                                     float* __restrict__ al_s,      // [M*8]
                                                     float* __restrict__ al_d) {    // [M*8]
  __shared__ u16 As[2][64 * 32];    // 8 KB
  __shared__ u16 Bs[2][256 * 32];   // 32 KB
  const int M = N_NODES;
  int bm = blockIdx.x * 64;
  int t = threadIdx.x;
  int lane = t & 63, wave = t >> 6;
  int wm = (wave & 1) * 32, wn = (wave >> 1) * 128;
  int lr = lane & 15;

  int arow = t >> 2;
  int akofs = (t & 3) * 8;
  int garow = bm + arow; if (garow >= M) garow = M - 1;
  const float* xrow = &X[(size_t)garow * IN_CH + akofs];

  int brow_base = wave * 64;
  int blrow = lane >> 2;
  int bkofs = (lane & 3) * 8;

  int kq = (lane >> 4) * 8;

  f32x4 acc[2][8] = {};

  // ---- prologue: stage k0=0 into buffer 0
  #pragma unroll
  for (int q = 0; q < 4; ++q) {
    int r0 = brow_base + q * 16;
    __builtin_amdgcn_global_load_lds(
        (const __attribute__((address_space(1))) void*)&BT[(size_t)(r0 + blrow) * IN_CH + bkofs],
        (__attribute__((address_space(3))) void*)&Bs[0][r0 * 32], 16, 0, 0);
  }
  {
    float4 v0 = *(const float4*)xrow;
    float4 v1 = *(const float4*)(xrow + 4);
    uint4 o;
    o.x = pack2(v0.x, v0.y); o.y = pack2(v0.z, v0.w);
    o.z = pack2(v1.x, v1.y); o.w = pack2(v1.z, v1.w);
    *(uint4*)&As[0][arow * 32 + akofs] = o;
  }
  asm volatile("s_waitcnt vmcnt(0) lgkmcnt(0)" ::: "memory");
  __builtin_amdgcn_s_barrier();
  __builtin_amdgcn_sched_barrier(0);

  int cur = 0;
  for (int k0 = 32; k0 < IN_CH; k0 += 32) {
    int nxt = cur ^ 1;
    float4 v0 = *(const float4*)(xrow + k0);
    float4 v1 = *(const float4*)(xrow + k0 + 4);
    #pragma unroll
    for (int q = 0; q < 4; ++q) {
      int r0 = brow_base + q * 16;
      __builtin_amdgcn_global_load_lds(
          (const __attribute__((address_space(1))) void*)&BT[(size_t)(r0 + blrow) * IN_CH + k0 + bkofs],
          (__attribute__((address_space(3))) void*)&Bs[nxt][r0 * 32], 16, 0, 0);
    }
    bf16x8 af[2], bfr[8];
    #pragma unroll
    for (int i = 0; i < 2; ++i)
      af[i] = *(const bf16x8*)&As[cur][(wm + i * 16 + lr) * 32 + kq];
    #pragma unroll
    for (int j = 0; j < 8; ++j)
      bfr[j] = *(const bf16x8*)&Bs[cur][(wn + j * 16 + lr) * 32 + kq];
    #pragma unroll
    for (int i = 0; i < 2; ++i)
      #pragma unroll
      for (int j = 0; j < 8; ++j)
        acc[i][j] = __builtin_amdgcn_mfma_f32_16x16x32_bf16(af[i], bfr[j], acc[i][j], 0, 0, 0);
    uint4 o;
    o.x = pack2(v0.x, v0.y); o.y = pack2(v0.z, v0.w);
    o.z = pack2(v1.x, v1.y); o.w = pack2(v1.z, v1.w);
    *(uint4*)&As[nxt][arow * 32 + akofs] = o;
    asm volatile("s_waitcnt vmcnt(0) lgkmcnt(0)" ::: "memory");
    __builtin_amdgcn_s_barrier();
    __builtin_amdgcn_sched_barrier(0);
    cur = nxt;
  }

  // last K-step: compute only
  {
    bf16x8 af[2], bfr[8];
    #pragma unroll
    for (int i = 0; i < 2; ++i)
      af[i] = *(const bf16x8*)&As[cur][(wm + i * 16 + lr) * 32 + kq];
    #pragma unroll
    for (int j = 0; j < 8; ++j)
      bfr[j] = *(const bf16x8*)&Bs[cur][(wn + j * 16 + lr) * 32 + kq];
    #pragma unroll
    for (int i = 0; i < 2; ++i)
      #pragma unroll
      for (int j = 0; j < 8; ++j)
        acc[i][j] = __builtin_amdgcn_mfma_f32_16x16x32_bf16(af[i], bfr[j], acc[i][j], 0, 0, 0);
  }

  // C-write
  #pragma unroll
  for (int i = 0; i < 2; ++i) {
    #pragma unroll
    for (int j = 0; j < 8; ++j) {
      int col = wn + j * 16 + lr;
      int rowb = bm + wm + i * 16 + (lane >> 4) * 4;
      #pragma unroll
      for (int r = 0; r < 4; ++r) {
        int row = rowb + r;
        if (row < M) Cb[(size_t)row * D1 + col] = f2bf(acc[i][j][r]);
      }
    }
  }

  // fused al1: per (i,r) fragment-row dot with att cols; wave covers heads hbase..hbase+3.
  float as_r[8], ad_r[8];
  #pragma unroll
  for (int j = 0; j < 8; ++j) {
    as_r[j] = AS[wn + j * 16 + lr];
    ad_r[j] = AD[wn + j * 16 + lr];
  }
  int hbase = wn >> 5;   // 0 or 4
  int c = lr;
  #pragma unroll
  for (int i = 0; i < 2; ++i) {
    #pragma unroll
    for (int r = 0; r < 4; ++r) {
      float ps0 = acc[i][0][r] * as_r[0] + acc[i][1][r] * as_r[1];
      float ps1 = acc[i][2][r] * as_r[2] + acc[i][3][r] * as_r[3];
      float ps2 = acc[i][4][r] * as_r[4] + acc[i][5][r] * as_r[5];
      float ps3 = acc[i][6][r] * as_r[6] + acc[i][7][r] * as_r[7];
      float pd0 = acc[i][0][r] * ad_r[0] + acc[i][1][r] * ad_r[1];
      float pd1 = acc[i][2][r] * ad_r[2] + acc[i][3][r] * ad_r[3];
      float pd2 = acc[i][4][r] * ad_r[4] + acc[i][5][r] * ad_r[5];
      float pd3 = acc[i][6][r] * ad_r[6] + acc[i][7][r] * ad_r[7];
      #pragma unroll
      for (int s = 1; s < 16; s <<= 1) {
        ps0 += __shfl_xor(ps0, s, 64); ps1 += __shfl_xor(ps1, s, 64);
        ps2 += __shfl_xor(ps2, s, 64); ps3 += __shfl_xor(ps3, s, 64);
        pd0 += __shfl_xor(pd0, s, 64); pd1 += __shfl_xor(pd1, s, 64);
        pd2 += __shfl_xor(pd2, s, 64); pd3 += __shfl_xor(pd3, s, 64);
      }
      int row = bm + wm + i * 16 + (lane >> 4) * 4 + r;
      if (c < 4 && row < M) {
        float ps = (c == 0) ? ps0 : (c == 1) ? ps1 : (c == 2) ? ps2 : ps3;
        float pd = (c == 0) ? pd0 : (c == 1) ? pd1 : (c == 2) ? pd2 : pd3;
        al_s[(size_t)row * 8 + hbase + c] = ps;
        al_d[(size_t)row * 8 + hbase + c] = pd;
      }
    }
  }
}

// ---------------- layer-1 aggregate + bias + ELU (round-1 best form) ----------------
__global__ __launch_bounds__(256) void k_agg1(const int* __restrict__ cnt,
                                              const u32* __restrict__ buck,
                                              const float* __restrict__ al_s,
                                              const float* __restrict__ al_d,
                                              const u16* __restrict__ h1b,
                                              const float* __restrict__ b1,
                                              u32* __restrict__ x2b) {
  int node = (blockIdx.x * 256 + threadIdx.x) >> 6;
  int lane = threadIdx.x & 63;
  if (node >= N_NODES) return;
  int cn = cnt[node]; if (cn > CAP) cn = CAP;
  const u32* br = &buck[(size_t)node * CAP];
  int h3 = lane >> 3;
  float ad = al_d[node * 8 + h3];
  size_t choff = (size_t)lane * 4;
  float dsum = 0.f;
  float4 acc = make_float4(0.f, 0.f, 0.f, 0.f);
  int j = 0;
  for (; j + 8 <= cn; j += 8) {
    int s0 = br[j + 0], s1 = br[j + 1], s2 = br[j + 2], s3 = br[j + 3];
    int s4 = br[j + 4], s5 = br[j + 5], s6 = br[j + 6], s7 = br[j + 7];
    float e0 = al_s[s0 * 8 + h3] + ad, e1 = al_s[s1 * 8 + h3] + ad;
    float e2 = al_s[s2 * 8 + h3] + ad, e3 = al_s[s3 * 8 + h3] + ad;
    float e4 = al_s[s4 * 8 + h3] + ad, e5 = al_s[s5 * 8 + h3] + ad;
    float e6 = al_s[s6 * 8 + h3] + ad, e7 = al_s[s7 * 8 + h3] + ad;
    uint2 hv0 = *(const uint2*)&h1b[(size_t)s0 * D1 + choff];
    uint2 hv1 = *(const uint2*)&h1b[(size_t)s1 * D1 + choff];
    uint2 hv2 = *(const uint2*)&h1b[(size_t)s2 * D1 + choff];
    uint2 hv3 = *(const uint2*)&h1b[(size_t)s3 * D1 + choff];
    uint2 hv4 = *(const uint2*)&h1b[(size_t)s4 * D1 + choff];
    uint2 hv5 = *(const uint2*)&h1b[(size_t)s5 * D1 + choff];
    uint2 hv6 = *(const uint2*)&h1b[(size_t)s6 * D1 + choff];
    uint2 hv7 = *(const uint2*)&h1b[(size_t)s7 * D1 + choff];
    e0 = (e0 > 0.f) ? e0 : NEG * e0;  e1 = (e1 > 0.f) ? e1 : NEG * e1;
    e2 = (e2 > 0.f) ? e2 : NEG * e2;  e3 = (e3 > 0.f) ? e3 : NEG * e3;
    e4 = (e4 > 0.f) ? e4 : NEG * e4;  e5 = (e5 > 0.f) ? e5 : NEG * e5;
    e6 = (e6 > 0.f) ? e6 : NEG * e6;  e7 = (e7 > 0.f) ? e7 : NEG * e7;
    float pp0 = __expf(e0), pp1 = __expf(e1), pp2 = __expf(e2), pp3 = __expf(e3);
    float pp4 = __expf(e4), pp5 = __expf(e5), pp6 = __expf(e6), pp7 = __expf(e7);
    dsum += ((pp0 + pp1) + (pp2 + pp3)) + ((pp4 + pp5) + (pp6 + pp7));
    acc.x += pp0 * bflo(hv0.x) + pp1 * bflo(hv1.x) + pp2 * bflo(hv2.x) + pp3 * bflo(hv3.x)
           + pp4 * bflo(hv4.x) + pp5 * bflo(hv5.x) + pp6 * bflo(hv6.x) + pp7 * bflo(hv7.x);
    acc.y += pp0 * bfhi(hv0.x) + pp1 * bfhi(hv1.x) + pp2 * bfhi(hv2.x) + pp3 * bfhi(hv3.x)
           + pp4 * bfhi(hv4.x) + pp5 * bfhi(hv5.x) + pp6 * bfhi(hv6.x) + pp7 * bfhi(hv7.x);
    acc.z += pp0 * bflo(hv0.y) + pp1 * bflo(hv1.y) + pp2 * bflo(hv2.y) + pp3 * bflo(hv3.y)
           + pp4 * bflo(hv4.y) + pp5 * bflo(hv5.y) + pp6 * bflo(hv6.y) + pp7 * bflo(hv7.y);
    acc.w += pp0 * bfhi(hv0.y) + pp1 * bfhi(hv1.y) + pp2 * bfhi(hv2.y) + pp3 * bfhi(hv3.y)
           + pp4 * bfhi(hv4.y) + pp5 * bfhi(hv5.y) + pp6 * bfhi(hv6.y) + pp7 * bfhi(hv7.y);
  }
  for (; j < cn; ++j) {
    int s0 = br[j];
    float e0 = al_s[s0 * 8 + h3] + ad;
    e0 = (e0 > 0.f) ? e0 : NEG * e0;
    float pp0 = __expf(e0);
    uint2 hv0 = *(const uint2*)&h1b[(size_t)s0 * D1 + choff];
    dsum += pp0;
    acc.x += pp0 * bflo(hv0.x);
    acc.y += pp0 * bfhi(hv0.x);
    acc.z += pp0 * bflo(hv0.y);
    acc.w += pp0 * bfhi(hv0.y);
  }
  float inv = 1.f / (dsum + 1e-16f);
  float4 bb = *(const float4*)&b1[lane * 4];
  float vx = acc.x * inv + bb.x; vx = vx > 0.f ? vx : __expf(vx) - 1.f;
  float vy = acc.y * inv + bb.y; vy = vy > 0.f ? vy : __expf(vy) - 1.f;
  float vz = acc.z * inv + bb.z; vz = vz > 0.f ? vz : __expf(vz) - 1.f;
  float vw = acc.w * inv + bb.w; vw = vw > 0.f ? vw : __expf(vw) - 1.f;
  ((uint2*)x2b)[(size_t)node * 64 + lane] = make_uint2(pack2(vx, vy), pack2(vz, vw));
}

// ---------------- GEMM2 (bf16 MFMA, ONE-SHOT panel stage, 1 barrier + FUSED al2) ----------------
__global__ __launch_bounds__(256) void k_gemm2_mfma(const u16* __restrict__ A,     // [M,256] bf16
                                                    const u16* __restrict__ W2T,   // [48][256] bf16
                                                    const float* __restrict__ AS2, // att_src2 [40]
                                                    const float* __restrict__ AD2, // att_dst2 [40]
                                                    u16* __restrict__ h2b,         // [M,40] bf16
                                                    float* __restrict__ al_s2,     // [M]
                                                    float* __restrict__ al_d2) {   // [M]
  __shared__ u16 As[8][64 * 32];        // 32 KB: 8 K-tiles of [64 rows][32 cols]
  const int M = N_NODES;
  int bm = blockIdx.x * 64;
  int t = threadIdx.x;
  int lane = t & 63, wave = t >> 6;
  int wm = wave * 16;
  int lr = lane & 15;
  int kq = (lane >> 4) * 8;

  // one-shot stage: per tile, wave w covers rows wm..wm+15 (lane>>2), cols (lane&3)*8
  {
    int srow = bm + wm + (lane >> 2); if (srow >= M) srow = M - 1;
    int skof = (lane & 3) * 8;
    const u16* ap = &A[(size_t)srow * D1 + skof];
    #pragma unroll
    for (int tt = 0; tt < 8; ++tt) {
      __builtin_amdgcn_global_load_lds(
          (const __attribute__((address_space(1))) void*)(ap + tt * 32),
          (__attribute__((address_space(3))) void*)&As[tt][wm * 32], 16, 0, 0);
    }
  }
  asm volatile("s_waitcnt vmcnt(0) lgkmcnt(0)" ::: "memory");
  __builtin_amdgcn_s_barrier();
  __builtin_amdgcn_sched_barrier(0);

  const u16* wp = &W2T[(size_t)lr * D1 + kq];   // + j*16*D1 per frag, + tt*32 per step
  f32x4 acc[3] = {};
  #pragma unroll
  for (int tt = 0; tt < 8; ++tt) {
    bf16x8 af = *(const bf16x8*)&As[tt][(wm + lr) * 32 + kq];
    bf16x8 bfr[3];
    #pragma unroll
    for (int j = 0; j < 3; ++j)
      bfr[j] = *(const bf16x8*)(wp + (size_t)j * 16 * D1 + tt * 32);
    #pragma unroll
    for (int j = 0; j < 3; ++j)
      acc[j] = __builtin_amdgcn_mfma_f32_16x16x32_bf16(af, bfr[j], acc[j], 0, 0, 0);
  }

  // C-write
  #pragma unroll
  for (int j = 0; j < 3; ++j) {
    int col = j * 16 + lr;
    if (col >= NCLS) continue;
    int rowb = bm + wm + (lane >> 4) * 4;
    #pragma unroll
    for (int r = 0; r < 4; ++r) {
      int row = rowb + r;
      if (row < M) h2b[(size_t)row * NCLS + col] = f2bf(acc[j][r]);
    }
  }

  // fused al2
  float as2_r[3], ad2_r[3];
  #pragma unroll
  for (int j = 0; j < 3; ++j) {
    int col = j * 16 + lr;
    as2_r[j] = (col < NCLS) ? AS2[col] : 0.f;
    ad2_r[j] = (col < NCLS) ? AD2[col] : 0.f;
  }
  #pragma unroll
  for (int r = 0; r < 4; ++r) {
    float ps = acc[0][r] * as2_r[0] + acc[1][r] * as2_r[1] + acc[2][r] * as2_r[2];
    float pd = acc[0][r] * ad2_r[0] + acc[1][r] * ad2_r[1] + acc[2][r] * ad2_r[2];
    #pragma unroll
    for (int s = 1; s < 16; s <<= 1) {
      ps += __shfl_xor(ps, s, 64);
      pd += __shfl_xor(pd, s, 64);
    }
    int row = bm + wm + (lane >> 4) * 4 + r;
    if (row < M) {
      if (lr == 0) al_s2[row] = ps;
      else if (lr == 1) al_d2[row] = pd;
    }
  }
}

// ---------------- layer-2 aggregate + bias: 2 NODES PER WAVE (32-lane halves) ----------------
// agg2 has no cross-lane reduction (each lane owns its column pair); only 20 of 64
// lanes were active. 32-lane halves double useful-lane fraction and HALVE wave count
// (50K -> 25K) at identical per-edge transaction count.
__global__ __launch_bounds__(256) void k_agg2(const int* __restrict__ cnt,
                                              const u32* __restrict__ buck,
                                              const float* __restrict__ al_s,
                                              const float* __restrict__ al_d,
                                              const u32* __restrict__ h2p,
                                              const float* __restrict__ b2,
                                              float* __restrict__ out) {
  int node = (blockIdx.x * 256 + threadIdx.x) >> 5;
  int lane = threadIdx.x & 31;
  if (node >= N_NODES) return;
  int cn = cnt[node]; if (cn > CAP) cn = CAP;
  const u32* br = &buck[(size_t)node * CAP];
  float ad = al_d[node];
  int cl = (lane < NCLS / 2) ? lane : 0;
  float dsum = 0.f, accl = 0.f, acch = 0.f;
  int j = 0;
  for (; j + 4 <= cn; j += 4) {
    int s0 = br[j + 0], s1 = br[j + 1], s2 = br[j + 2], s3 = br[j + 3];
    float e0 = al_s[s0] + ad, e1 = al_s[s1] + ad;
    float e2 = al_s[s2] + ad, e3 = al_s[s3] + ad;
    u32 g0 = h2p[(size_t)s0 * (NCLS / 2) + cl];
    u32 g1 = h2p[(size_t)s1 * (NCLS / 2) + cl];
    u32 g2 = h2p[(size_t)s2 * (NCLS / 2) + cl];
    u32 g3 = h2p[(size_t)s3 * (NCLS / 2) + cl];
    e0 = (e0 > 0.f) ? e0 : NEG * e0;
    e1 = (e1 > 0.f) ? e1 : NEG * e1;
    e2 = (e2 > 0.f) ? e2 : NEG * e2;
    e3 = (e3 > 0.f) ? e3 : NEG * e3;
    float p0 = __expf(e0), p1 = __expf(e1), p2 = __expf(e2), p3 = __expf(e3);
    dsum += (p0 + p1) + (p2 + p3);
    accl += p0 * bflo(g0) + p1 * bflo(g1) + p2 * bflo(g2) + p3 * bflo(g3);
    acch += p0 * bfhi(g0) + p1 * bfhi(g1) + p2 * bfhi(g2) + p3 * bfhi(g3);
  }
  for (; j < cn; ++j) {
    int s0 = br[j];
    float e0 = al_s[s0] + ad;
    e0 = (e0 > 0.f) ? e0 : NEG * e0;
    float p0 = __expf(e0);
    u32 g0 = h2p[(size_t)s0 * (NCLS / 2) + cl];
    dsum += p0;
    accl += p0 * bflo(g0);
    acch += p0 * bfhi(g0);
  }
  float inv = 1.f / (dsum + 1e-16f);
  if (lane < NCLS / 2) {
    out[(size_t)node * NCLS + 2 * lane]     = accl * inv + b2[2 * lane];
    out[(size_t)node * NCLS + 2 * lane + 1] = acch * inv + b2[2 * lane + 1];
  }
}

extern "C" void kernel_launch(void* const* d_in, const int* in_sizes, int n_in,
                              void* d_out, int out_size, void* d_ws, size_t ws_size,
                              hipStream_t stream) {
  const float* x   = (const float*)d_in[0];
  const int*   ei  = (const int*)d_in[1];
  const float* W1  = (const float*)d_in[2];
  const float* as1 = (const float*)d_in[3];
  const float* ad1 = (const float*)d_in[4];
  const float* b1  = (const float*)d_in[5];
  const float* W2  = (const float*)d_in[6];
  const float* as2 = (const float*)d_in[7];
  const float* ad2 = (const float*)d_in[8];
  const float* b2  = (const float*)d_in[9];
  float* out = (float*)d_out;

  // workspace carve-up (~75 MB of the 400 MB ws)
  char* p = (char*)d_ws;
  auto alloc = [&](size_t bytes) { char* r = p; p += (bytes + 15) & ~size_t(15); return r; };
  u16*  h1b    = (u16*)alloc((size_t)N_NODES * D1 * 2);      // 25.6 MB bf16
  u32*  x2b    = (u32*)alloc((size_t)N_NODES * D1 * 2);      // 25.6 MB bf16 pairs
  u16*  h2b    = (u16*)alloc((size_t)N_NODES * NCLS * 2);    // 4 MB bf16
  float* al_s1 = (float*)alloc((size_t)N_NODES * 8 * 4);
  float* al_d1 = (float*)alloc((size_t)N_NODES * 8 * 4);
  float* al_s2 = (float*)alloc((size_t)N_NODES * 4);
  float* al_d2 = (float*)alloc((size_t)N_NODES * 4);
  int*   cnt   = (int*)alloc((size_t)N_NODES * 4);
  u32*   buck  = (u32*)alloc((size_t)N_NODES * CAP * 4);     // 12.8 MB
  u16*   w1t   = (u16*)alloc((size_t)D1 * IN_CH * 2);
  u16*   w2t   = (u16*)alloc((size_t)NCLS_P * D1 * 2);

  hipMemsetAsync(cnt, 0, (size_t)N_NODES * 4, stream);

  const int WTOT = D1 * IN_CH + NCLS_P * D1;
  const int NB_CAST = (WTOT + 255) / 256;
  k_prep<<<NB_BUCKET + NB_CAST, 256, 0, stream>>>(ei, cnt, buck, W1, W2, w1t, w2t);

  k_gemm1_fused<<<(N_NODES + 63) / 64, 256, 0, stream>>>(x, w1t, as1, ad1, h1b, al_s1, al_d1);
  k_agg1<<<(N_NODES + 3) / 4, 256, 0, stream>>>(cnt, buck, al_s1, al_d1, h1b, b1, x2b);

  k_gemm2_mfma<<<(N_NODES + 63) / 64, 256, 0, stream>>>((const u16*)x2b, w2t, as2, ad2, h2b, al_s2, al_d2);
  k_agg2<<<(N_NODES + 7) / 8, 256, 0, stream>>>(cnt, buck, al_s2, al_d2, (const u32*)h2b, b2, out);
}